// Round 6
// baseline (207.724 us; speedup 1.0000x reference)
//
#include <hip/hip_runtime.h>
#include <hip/hip_bf16.h>
#include <stdint.h>

#define DEVI __device__ __forceinline__

typedef __bf16 bf16x8 __attribute__((ext_vector_type(8)));
typedef float f32x4 __attribute__((ext_vector_type(4)));
typedef unsigned short ushort8v __attribute__((ext_vector_type(8)));

static constexpr int SEQ = 4096;
static constexpr int DIM_ = 1024;
static constexpr int NH = 16;
static constexpr int HD_ = 64;
static constexpr float SCALE_ = 0.125f;  // 1/sqrt(64)

DEVI unsigned short f2bf(float f) {
  __hip_bfloat16 h = __float2bfloat16(f);
  return __builtin_bit_cast(unsigned short, h);
}

// ---------------------------------------------------------------- conversions

__global__ void k_cvt_bf16(const float* __restrict__ in, unsigned short* __restrict__ out) {
  int i = (blockIdx.x * 256 + threadIdx.x) * 4;
  float4 v = *reinterpret_cast<const float4*>(in + i);
  ushort4 o;
  o.x = f2bf(v.x); o.y = f2bf(v.y); o.z = f2bf(v.z); o.w = f2bf(v.w);
  *reinterpret_cast<ushort4*>(out + i) = o;
}

// in: K x N f32 (row-major), out: N x K bf16 (row-major)
__global__ void k_transpose_cvt(const float* __restrict__ in, unsigned short* __restrict__ out,
                                int K, int N) {
  __shared__ float tile[64][65];
  const int n0 = blockIdx.x * 64, k0 = blockIdx.y * 64;
  const int tr = threadIdx.x >> 6, tc = threadIdx.x & 63;
#pragma unroll
  for (int p = 0; p < 16; ++p) {
    int r = p * 4 + tr;
    tile[r][tc] = in[(size_t)(k0 + r) * N + n0 + tc];
  }
  __syncthreads();
#pragma unroll
  for (int p = 0; p < 16; ++p) {
    int r = p * 4 + tr;  // output row (n index)
    out[(size_t)(n0 + r) * K + k0 + tc] = f2bf(tile[tc][r]);
  }
}

// ---------------------------------------------------------------- 256x256 deep-pipelined GEMM
// A: MxK bf16 row-major. Bt: NxK bf16 row-major. K multiple of 32 (NT>=4).
// Ring of 4 K-tile slots (BK=32); counted vmcnt(8): tiles t+1,t+2 always in flight.
// LDS swizzle: element (r, c8) of a slot stored at byte r*64 + ((c8 ^ ((r>>1)&3))<<4).
//   - write side: linear gload_lds dest + inverse-swizzled per-lane GLOBAL source
//   - read side : same XOR on ds_read address  -> 2 lanes/bank (conflict-free)
// MODE 0: outF[row*N+col] = acc + bias[col]  (f32)
// MODE 1: qkv scatter -> outQ/outK/outV bf16, layout [b][h][s][d]

DEVI void load16_lds(const void* g, void* l) {
  __builtin_amdgcn_global_load_lds((__attribute__((address_space(1))) void*)(g),
                                   (__attribute__((address_space(3))) void*)(l),
                                   16, 0, 0);
}

template <int MODE>
__global__ __launch_bounds__(512, 2)
void k_gemm256(const unsigned short* __restrict__ A,
               const unsigned short* __restrict__ Bt,
               const float* __restrict__ bias,
               float* __restrict__ outF,
               unsigned short* __restrict__ outQ,
               unsigned short* __restrict__ outK,
               unsigned short* __restrict__ outV,
               int M, int N, int K) {
  __shared__ alignas(16) unsigned short As[4][8192];  // 4 slots x 16 KB
  __shared__ alignas(16) unsigned short Bs[4][8192];

  const int tid = threadIdx.x;
  const int wave = tid >> 6, lane = tid & 63;
  const int wr = wave >> 2, wc = wave & 3;   // 2 (M) x 4 (N) wave grid
  const int l15 = lane & 15, q = lane >> 4;

  // XCD-aware block swizzle (grid counts are multiples of 8 here)
  const int gm = M >> 8;
  const int gn = N >> 8;
  const int nwg = gm * gn;
  int wg = blockIdx.y * gridDim.x + blockIdx.x;
  wg = (wg & 7) * (nwg >> 3) + (wg >> 3);
  const int bm = (wg % gm) * 256;
  const int bn = (wg / gm) * 256;

  const int NT = K >> 5;

  // ---- staging source (per lane): wave w stages 16-row segs {2w, 2w+1} of A and B.
  // lane i -> row = seg*16 + (i>>2), logical chunk c8 = (i&3) ^ ((i>>3)&3)
  const int c8 = (lane & 3) ^ ((lane >> 3) & 3);
  const int r0 = wave * 32 + (lane >> 2);
  const unsigned short* aG0 = A + (size_t)(bm + r0) * K + c8 * 8;
  const unsigned short* aG1 = A + (size_t)(bm + r0 + 16) * K + c8 * 8;
  const unsigned short* bG0 = Bt + (size_t)(bn + r0) * K + c8 * 8;
  const unsigned short* bG1 = Bt + (size_t)(bn + r0 + 16) * K + c8 * 8;
  const int ldsOff = wave * 1024;  // seg 2w at byte 2048*w = ushort 1024*w

  // ---- read-side byte offsets (within a slot)
  const int sw = (q ^ ((l15 >> 1) & 3)) << 4;
  const int aRdByte = (wr * 128 + l15) * 64 + sw;
  const int bRdByte = (wc * 64 + l15) * 64 + sw;

  f32x4 acc[8][4] = {};

  // ---- prologue: stage tiles 0,1,2 into slots 0,1,2 (12 loads/wave in flight)
#pragma unroll
  for (int t = 0; t < 3; ++t) {
    const int kk = t * 32;
    load16_lds(aG0 + kk, &As[t][ldsOff]);
    load16_lds(aG1 + kk, &As[t][ldsOff + 512]);
    load16_lds(bG0 + kk, &Bs[t][ldsOff]);
    load16_lds(bG1 + kk, &Bs[t][ldsOff + 512]);
  }

#pragma unroll 1
  for (int t = 0; t < NT; ++t) {
    // retire tile t's 4 loads; keep t+1,t+2 (8 loads) in flight — never drain
    asm volatile("s_waitcnt vmcnt(8)" ::: "memory");
    __builtin_amdgcn_s_barrier();

    // stage tile t+3 (clamped dummy near the end keeps vmcnt arithmetic uniform;
    // its slot is provably never read again)
    {
      const int tt = (t + 3 < NT) ? (t + 3) : t;
      const int kk = tt * 32;
      const int s3 = (t + 3) & 3;
      load16_lds(aG0 + kk, &As[s3][ldsOff]);
      load16_lds(aG1 + kk, &As[s3][ldsOff + 512]);
      load16_lds(bG0 + kk, &Bs[s3][ldsOff]);
      load16_lds(bG1 + kk, &Bs[s3][ldsOff + 512]);
    }

    const int s = t & 3;
    const char* aB = reinterpret_cast<const char*>(&As[s][0]) + aRdByte;
    const char* bB = reinterpret_cast<const char*>(&Bs[s][0]) + bRdByte;
    bf16x8 bfr[4], af[8];
#pragma unroll
    for (int n = 0; n < 4; ++n)
      bfr[n] = *reinterpret_cast<const bf16x8*>(bB + n * 1024);
#pragma unroll
    for (int m = 0; m < 8; ++m)
      af[m] = *reinterpret_cast<const bf16x8*>(aB + m * 1024);

    __builtin_amdgcn_s_setprio(1);
#pragma unroll
    for (int m = 0; m < 8; ++m)
#pragma unroll
      for (int n = 0; n < 4; ++n)
        acc[m][n] = __builtin_amdgcn_mfma_f32_16x16x32_bf16(af[m], bfr[n], acc[m][n], 0, 0, 0);
    __builtin_amdgcn_s_setprio(0);
  }

  // ---- epilogue: D frag mapping col = lane&15, row = (lane>>4)*4 + j
  const int fr0 = q * 4;
#pragma unroll
  for (int m = 0; m < 8; ++m) {
#pragma unroll
    for (int n = 0; n < 4; ++n) {
      const int col = bn + wc * 64 + n * 16 + l15;
      const float bv = bias[col];
#pragma unroll
      for (int j = 0; j < 4; ++j) {
        const int row = bm + wr * 128 + m * 16 + fr0 + j;
        const float v = acc[m][n][j] + bv;
        if constexpr (MODE == 0) {
          outF[(size_t)row * N + col] = v;
        } else {
          const int t = col >> 10;          // 0:Q 1:K 2:V
          const int hh = (col >> 6) & 15;   // head
          const int d = col & 63;
          const int b = row >> 12;
          const int ss = row & 4095;
          unsigned short* dst = (t == 0) ? outQ : (t == 1) ? outK : outV;
          dst[((size_t)(b * NH + hh) * SEQ + ss) * HD_ + d] = f2bf(v);
        }
      }
    }
  }
}

// ---------------------------------------------------------------- grouping
// routes[s][0] == stable-argsort leader of the equal-Cantor-coord class.
// Verify exact row equality vs leader; mismatch -> singleton group.

__global__ void k_gid(const int* __restrict__ routes, int* __restrict__ gid, int* __restrict__ cnt) {
  const int s = blockIdx.x * 256 + threadIdx.x;
  const int lead = routes[s * 64];
  int g = s;
  if (lead >= 0 && lead < SEQ && lead != s) {
    bool eq = true;
    const int4* a = reinterpret_cast<const int4*>(routes + (size_t)s * 64);
    const int4* b = reinterpret_cast<const int4*>(routes + (size_t)lead * 64);
#pragma unroll
    for (int i = 0; i < 16; ++i) {
      int4 x = a[i], y = b[i];
      eq = eq && (x.x == y.x) && (x.y == y.y) && (x.z == y.z) && (x.w == y.w);
    }
    if (eq) g = lead;
  }
  gid[s] = g;
  atomicAdd(&cnt[g], 1);
}

__global__ void k_tilebase(const int* __restrict__ cnt, int* __restrict__ tileBase,
                           int* __restrict__ nTiles) {
  const int g = blockIdx.x * 256 + threadIdx.x;
  const int c = cnt[g];
  if (c > 0) {
    tileBase[g] = atomicAdd(nTiles, (c + 15) >> 4);
  }
}

__global__ void k_scatter(const int* __restrict__ gid, const int* __restrict__ tileBase,
                          int* __restrict__ pos, int* __restrict__ tileQ,
                          int* __restrict__ tileLead) {
  const int s = blockIdx.x * 256 + threadIdx.x;
  const int g = gid[s];
  const int p = atomicAdd(&pos[g], 1);
  const int tile = tileBase[g] + (p >> 4);
  tileQ[tile * 16 + (p & 15)] = s;
  if ((p & 15) == 0) tileLead[tile] = g;
}

// ---------------------------------------------------------------- grouped MFMA attention
// Block: 4 waves; wave w handles bh = blockIdx.y*8 + w*2 + {0,1} for tile blockIdx.x.
// Per wave: private 8KB KV LDS buffer (K for QK^T, then reused for V), P in stride-72 LDS.

__global__ __launch_bounds__(256)
void k_attn_grp(const unsigned short* __restrict__ Q,
                const unsigned short* __restrict__ Kb,
                const unsigned short* __restrict__ Vb,
                const int* __restrict__ routes,
                const int* __restrict__ tileQ,
                const int* __restrict__ tileLead,
                const int* __restrict__ nTilesPtr,
                unsigned short* __restrict__ att) {
  const int tile = blockIdx.x;
  if (tile >= *nTilesPtr) return;

  __shared__ int sMemRaw[16];
  __shared__ int sMemEff[16];
  __shared__ int sRoutes[64];
  __shared__ alignas(16) unsigned short sKV[4][4096];   // 32 KB
  __shared__ alignas(16) unsigned short sP[4][16 * 72]; // 9216 B

  const int tid = threadIdx.x;
  if (tid < 16) {
    const int v = tileQ[tile * 16 + tid];
    const int v0 = tileQ[tile * 16];
    sMemRaw[tid] = v;
    sMemEff[tid] = (v < 0) ? v0 : v;
  } else if (tid >= 64 && tid < 128) {
    const int lead = tileLead[tile];
    sRoutes[tid - 64] = routes[(size_t)lead * 64 + (tid - 64)];
  }
  __syncthreads();

  const int wave = tid >> 6, lane = tid & 63;
  unsigned short* KV = sKV[wave];
  unsigned short* P = sP[wave];
  const int hi = lane >> 4;    // 0..3
  const int l15 = lane & 15;
  const int l7 = lane & 7;
  const int rr = lane >> 3;    // 0..7 (staging row-in-iter)

#pragma unroll 1
  for (int ih = 0; ih < 2; ++ih) {
    const int bh = blockIdx.y * 8 + wave * 2 + ih;
    const size_t base = (size_t)bh * (SEQ * HD_);

    __builtin_amdgcn_s_waitcnt(0);
    __builtin_amdgcn_sched_barrier(0);

    // ---- stage K (rot8). src chunk = (c' - (k&7)) & 7, k&7 == rr
    {
      const int sc = ((l7 - rr) & 7) * 8;
#pragma unroll
      for (int t = 0; t < 8; ++t) {
        const int rk = sRoutes[t * 8 + rr];
        load16_lds(Kb + base + (size_t)rk * HD_ + sc, &KV[t * 512]);
      }
    }

    // ---- Q fragments direct from global
    bf16x8 qa0, qa1;
    {
      const unsigned short* qrow = Q + base + (size_t)sMemEff[l15] * HD_ + hi * 8;
      qa0 = *reinterpret_cast<const bf16x8*>(qrow);
      qa1 = *reinterpret_cast<const bf16x8*>(qrow + 32);
    }
    __builtin_amdgcn_s_waitcnt(0);
    __builtin_amdgcn_sched_barrier(0);

    // ---- QK^T
    f32x4 accS[4] = {};
#pragma unroll
    for (int nb = 0; nb < 4; ++nb) {
      const int key = nb * 16 + l15;
      const int rot = 8 * (key & 7);
      const int ae0 = key * 64 + (((hi * 8) + rot) & 63);
      const int ae1 = key * 64 + (((32 + hi * 8) + rot) & 63);
      bf16x8 kf0 = *reinterpret_cast<const bf16x8*>(&KV[ae0]);
      bf16x8 kf1 = *reinterpret_cast<const bf16x8*>(&KV[ae1]);
      accS[nb] = __builtin_amdgcn_mfma_f32_16x16x32_bf16(qa0, kf0, accS[nb], 0, 0, 0);
      accS[nb] = __builtin_amdgcn_mfma_f32_16x16x32_bf16(qa1, kf1, accS[nb], 0, 0, 0);
    }

    // ---- softmax per row
#pragma unroll
    for (int jj = 0; jj < 4; ++jj) {
      float m = fmaxf(fmaxf(accS[0][jj], accS[1][jj]), fmaxf(accS[2][jj], accS[3][jj]));
#pragma unroll
      for (int o = 1; o < 16; o <<= 1) m = fmaxf(m, __shfl_xor(m, o));
      const float e0 = __expf((accS[0][jj] - m) * SCALE_);
      const float e1 = __expf((accS[1][jj] - m) * SCALE_);
      const float e2 = __expf((accS[2][jj] - m) * SCALE_);
      const float e3 = __expf((accS[3][jj] - m) * SCALE_);
      float sum = (e0 + e1) + (e2 + e3);
#pragma unroll
      for (int o = 1; o < 16; o <<= 1) sum += __shfl_xor(sum, o);
      const float rs = __builtin_amdgcn_rcpf(sum);
      const int row = hi * 4 + jj;
      P[row * 72 + 0 + l15] = f2bf(e0 * rs);
      P[row * 72 + 16 + l15] = f2bf(e1 * rs);
      P[row * 72 + 32 + l15] = f2bf(e2 * rs);
      P[row * 72 + 48 + l15] = f2bf(e3 * rs);
    }

    // ---- stage V (rot16) into same KV buffer
    asm volatile("s_waitcnt lgkmcnt(0)" ::: "memory");
    __builtin_amdgcn_sched_barrier(0);
    {
#pragma unroll
      for (int t = 0; t < 8; ++t) {
        const int rk = sRoutes[t * 8 + rr];
        const int sc = ((l7 - 2 * (t & 3)) & 7) * 8;
        load16_lds(Vb + base + (size_t)rk * HD_ + sc, &KV[t * 512]);
      }
    }
    __builtin_amdgcn_s_waitcnt(0);
    __builtin_amdgcn_sched_barrier(0);

    // ---- PV
    f32x4 accO[4] = {};
#pragma unroll
    for (int ks = 0; ks < 2; ++ks) {
      bf16x8 pf = *reinterpret_cast<const bf16x8*>(&P[l15 * 72 + ks * 32 + hi * 8]);
#pragma unroll
      for (int nb = 0; nb < 4; ++nb) {
        const int d = nb * 16 + l15;
        const int rot = (d + 16 * hi) & 63;
        bf16x8 vf;
#pragma unroll
        for (int j = 0; j < 8; ++j) {
          const int k = ks * 32 + hi * 8 + j;
          vf[j] = *reinterpret_cast<const __bf16*>(&KV[k * 64 + rot]);
        }
        accO[nb] = __builtin_amdgcn_mfma_f32_16x16x32_bf16(pf, vf, accO[nb], 0, 0, 0);
      }
    }

    // ---- epilogue: att[b][s][h*64 + d]
    const int b = bh >> 4, h = bh & 15;
#pragma unroll
    for (int jj = 0; jj < 4; ++jj) {
      const int sQ = sMemRaw[hi * 4 + jj];
      if (sQ >= 0) {
#pragma unroll
        for (int nb = 0; nb < 4; ++nb) {
          att[((size_t)(b * SEQ + sQ)) * DIM_ + h * HD_ + nb * 16 + l15] = f2bf(accO[nb][jj]);
        }
      }
    }
  }
}

// ---------------------------------------------------------------- launch

extern "C" void kernel_launch(void* const* d_in, const int* in_sizes, int n_in,
                              void* d_out, int out_size, void* d_ws, size_t ws_size,
                              hipStream_t stream) {
  (void)in_sizes; (void)n_in; (void)out_size; (void)ws_size;
  const float* x      = (const float*)d_in[0];
  const float* Wqkv   = (const float*)d_in[1];
  const float* bqkv   = (const float*)d_in[2];
  const float* Wout   = (const float*)d_in[3];
  const float* bout   = (const float*)d_in[4];
  const int*   routes = (const int*)d_in[5];
  float* out = (float*)d_out;

  uint8_t* ws = (uint8_t*)d_ws;
  unsigned short* wqkvT = (unsigned short*)(ws);              //  6,291,456 B (3072x1024 bf16)
  unsigned short* woutT = (unsigned short*)(ws + 6291456);    //  2,097,152 B (1024x1024 bf16)
  unsigned short* Qb    = (unsigned short*)(ws + 8388608);    // 16 MiB
  unsigned short* Kb    = (unsigned short*)(ws + 25165824);   // 16 MiB
  unsigned short* Vb    = (unsigned short*)(ws + 41943040);   // 16 MiB
  unsigned short* att   = (unsigned short*)(ws + 58720256);   // 16 MiB (end 75,497,472)

  // d_out (32 MiB f32): first 16 MiB = xb (dead after GEMM1); second half holds group
  // metadata (dead before GEMM2's output store touches it).
  unsigned short* xb = (unsigned short*)d_out;
  uint8_t* g0 = (uint8_t*)d_out + (16u << 20);
  int* gidArr   = (int*)(g0);                 // 16 KB
  int* cnt      = (int*)(g0 + 16384);         // 16 KB
  int* pos      = (int*)(g0 + 32768);         // 16 KB
  int* tileBase = (int*)(g0 + 49152);         // 16 KB
  int* nTiles   = (int*)(g0 + 65536);         // 4 B
  int* tileLead = (int*)(g0 + 81920);         // 16 KB
  int* tileQ    = (int*)(g0 + 98304);         // 256 KB

  hipMemsetAsync(cnt, 0, 16384, stream);
  hipMemsetAsync(pos, 0, 16384, stream);
  hipMemsetAsync(nTiles, 0, 4, stream);
  hipMemsetAsync(tileQ, 0xFF, 4096 * 16 * 4, stream);

  k_gid<<<16, 256, 0, stream>>>(routes, gidArr, cnt);
  k_tilebase<<<16, 256, 0, stream>>>(cnt, tileBase, nTiles);
  k_scatter<<<16, 256, 0, stream>>>(gidArr, tileBase, pos, tileQ, tileLead);

  k_cvt_bf16<<<8192, 256, 0, stream>>>(x, xb);
  k_transpose_cvt<<<dim3(48, 16), 256, 0, stream>>>(Wqkv, wqkvT, 1024, 3072);
  k_transpose_cvt<<<dim3(16, 16), 256, 0, stream>>>(Wout, woutT, 1024, 1024);

  k_gemm256<1><<<dim3(32, 12), 512, 0, stream>>>(xb, wqkvT, bqkv, nullptr, Qb, Kb, Vb,
                                                 8192, 3072, 1024);
  k_attn_grp<<<dim3(4096, 4), 256, 0, stream>>>(Qb, Kb, Vb, routes, tileQ, tileLead,
                                                nTiles, att);
  k_gemm256<0><<<dim3(32, 4), 512, 0, stream>>>(att, woutT, bout, out,
                                                nullptr, nullptr, nullptr, 8192, 1024, 1024);
}

// Round 7
// 178.761 us; speedup vs baseline: 1.1620x; 1.1620x over previous
//
#include <hip/hip_runtime.h>
#include <hip/hip_bf16.h>
#include <stdint.h>

#define DEVI __device__ __forceinline__

typedef __bf16 bf16x8 __attribute__((ext_vector_type(8)));
typedef float f32x4 __attribute__((ext_vector_type(4)));
typedef unsigned short ushort8v __attribute__((ext_vector_type(8)));

static constexpr int SEQ = 4096;
static constexpr int DIM_ = 1024;
static constexpr int NH = 16;
static constexpr int HD_ = 64;
static constexpr float SCALE_ = 0.125f;  // 1/sqrt(64)

DEVI unsigned short f2bf(float f) {
  __hip_bfloat16 h = __float2bfloat16(f);
  return __builtin_bit_cast(unsigned short, h);
}

// ---------------------------------------------------------------- conversions

__global__ void k_cvt_bf16(const float* __restrict__ in, unsigned short* __restrict__ out) {
  int i = (blockIdx.x * 256 + threadIdx.x) * 4;
  float4 v = *reinterpret_cast<const float4*>(in + i);
  ushort4 o;
  o.x = f2bf(v.x); o.y = f2bf(v.y); o.z = f2bf(v.z); o.w = f2bf(v.w);
  *reinterpret_cast<ushort4*>(out + i) = o;
}

// in: K x N f32 (row-major), out: N x K bf16 (row-major)
__global__ void k_transpose_cvt(const float* __restrict__ in, unsigned short* __restrict__ out,
                                int K, int N) {
  __shared__ float tile[64][65];
  const int n0 = blockIdx.x * 64, k0 = blockIdx.y * 64;
  const int tr = threadIdx.x >> 6, tc = threadIdx.x & 63;
#pragma unroll
  for (int p = 0; p < 16; ++p) {
    int r = p * 4 + tr;
    tile[r][tc] = in[(size_t)(k0 + r) * N + n0 + tc];
  }
  __syncthreads();
#pragma unroll
  for (int p = 0; p < 16; ++p) {
    int r = p * 4 + tr;  // output row (n index)
    out[(size_t)(n0 + r) * K + k0 + tc] = f2bf(tile[tc][r]);
  }
}

// ---------------------------------------------------------------- 256x256 8-phase GEMM (T2+T3+T4+T5)
// A: MxK bf16 row-major. Bt: NxK bf16 row-major. K multiple of 64, K>=128.
// BK=64; 2 K-tile double-buffer (128 KiB). 4 phases per K-tile:
//   phase p: {ds_read A-frags m=2p,2p+1 (+all B-frags at p0); stage one half-tile;
//             barrier; lgkmcnt(0); setprio(1); 16 MFMA; setprio(0); [p3: vmcnt(4)]; barrier}
// Stage schedule: p0/p1 = A-halves of tile t+1 (buf ~t), p2/p3 = B-halves of tile t+2
// (buf t's B region — dead after p0's reads + barrier generations). vmcnt never drains.
// LDS swizzle: chunk slot c holds logical chunk c ^ ((row>>1)&7); write side realized by
// pre-swizzled per-lane GLOBAL source (linear gload_lds dest); read side same XOR.
// MODE 0: outF[row*N+col] = acc + bias[col]  (f32)
// MODE 1: qkv scatter -> outQ/outK/outV bf16, layout [b][h][s][d]

DEVI void load16_lds(const void* g, void* l) {
  __builtin_amdgcn_global_load_lds((__attribute__((address_space(1))) void*)(g),
                                   (__attribute__((address_space(3))) void*)(l),
                                   16, 0, 0);
}

template <int MODE>
__global__ __launch_bounds__(512, 2)
void k_gemm8p(const unsigned short* __restrict__ A,
              const unsigned short* __restrict__ Bt,
              const float* __restrict__ bias,
              float* __restrict__ outF,
              unsigned short* __restrict__ outQ,
              unsigned short* __restrict__ outK,
              unsigned short* __restrict__ outV,
              int M, int N, int K) {
  // layout (ushort idx): buf b at b*32768; A-half h at +h*8192; B-half h at +16384+h*8192.
  // row stride 64 ushort (128 B); half = 128 rows.
  __shared__ alignas(16) unsigned short lds_[65536];  // 128 KiB

  const int tid = threadIdx.x;
  const int wave = tid >> 6, lane = tid & 63;
  const int wr = wave >> 2, wc = wave & 3;   // 2 (M) x 4 (N) wave grid
  const int l15 = lane & 15, q = lane >> 4;

  // XCD-aware block swizzle (grid counts are multiples of 8 here)
  const int gm = M >> 8;
  const int nwg = gm * (N >> 8);
  int wg = blockIdx.y * gridDim.x + blockIdx.x;
  wg = (wg & 7) * (nwg >> 3) + (wg >> 3);
  const int bm = (wg % gm) * 256;
  const int bn = (wg / gm) * 256;

  const int NT = K >> 6;
  const size_t K64 = (size_t)64 * K;

  // ---- staging source (per lane): row-in-64 = wave*8 + (lane>>3); slot chunk = lane&7.
  // logical chunk fetched = slot ^ ((row>>1)&7)  (r*64 offsets preserve &7 of row>>1)
  const int srow8 = wave * 8 + (lane >> 3);
  const int c_log = (lane & 7) ^ ((srow8 >> 1) & 7);
  const unsigned short* aSt = A + (size_t)(bm + srow8) * K + c_log * 8;
  const unsigned short* bSt = Bt + (size_t)(bn + srow8) * K + c_log * 8;

  // ---- read-side swizzled chunk offsets (ushort): chunk' = (ks*4+q) ^ ((l15>>1)&7)
  const int x7 = (l15 >> 1) & 7;
  const int sw0 = ((q ^ x7)) * 8;
  const int sw1 = (((q + 4) ^ x7)) * 8;

  f32x4 acc[8][4] = {};

  // ---- prologue: A(0) 4 loads, B(0) 4 loads, B(1) 4 loads  -> 12 in flight
  {
    unsigned short* a0 = lds_ + wave * 512;
    unsigned short* b0 = lds_ + 16384 + wave * 512;
    unsigned short* b1 = lds_ + 32768 + 16384 + wave * 512;
    load16_lds(aSt, a0);
    load16_lds(aSt + K64, a0 + 4096);
    load16_lds(aSt + 2 * K64, a0 + 8192);
    load16_lds(aSt + 3 * K64, a0 + 8192 + 4096);
    load16_lds(bSt, b0);
    load16_lds(bSt + K64, b0 + 4096);
    load16_lds(bSt + 2 * K64, b0 + 8192);
    load16_lds(bSt + 3 * K64, b0 + 8192 + 4096);
    load16_lds(bSt + 64, b1);
    load16_lds(bSt + K64 + 64, b1 + 4096);
    load16_lds(bSt + 2 * K64 + 64, b1 + 8192);
    load16_lds(bSt + 3 * K64 + 64, b1 + 8192 + 4096);
  }
  asm volatile("s_waitcnt vmcnt(4)" ::: "memory");  // tile 0 resident; B(1) in flight
  __builtin_amdgcn_s_barrier();

#pragma unroll 1
  for (int t = 0; t < NT; ++t) {
    const int bsel = t & 1;
    const unsigned short* aBase = lds_ + bsel * 32768 + wr * 8192 + l15 * 64;
    const unsigned short* bBase = lds_ + bsel * 32768 + 16384 + (wc >> 1) * 8192 +
                                  (wc & 1) * 4096 + l15 * 64;
    const size_t ka = (size_t)((t + 1 < NT) ? t + 1 : t) * 64;
    const size_t kb = (size_t)((t + 2 < NT) ? t + 2 : t) * 64;
    unsigned short* dstA = lds_ + (bsel ^ 1) * 32768 + wave * 512;
    unsigned short* dstB = lds_ + bsel * 32768 + 16384 + wave * 512;

    bf16x8 bfr[4][2];
#pragma unroll
    for (int p = 0; p < 4; ++p) {
      // ---- ds_read register subtile
      if (p == 0) {
#pragma unroll
        for (int n = 0; n < 4; ++n) {
          bfr[n][0] = *reinterpret_cast<const bf16x8*>(bBase + n * 1024 + sw0);
          bfr[n][1] = *reinterpret_cast<const bf16x8*>(bBase + n * 1024 + sw1);
        }
      }
      bf16x8 af[2][2];
#pragma unroll
      for (int mm = 0; mm < 2; ++mm) {
        af[mm][0] = *reinterpret_cast<const bf16x8*>(aBase + (2 * p + mm) * 1024 + sw0);
        af[mm][1] = *reinterpret_cast<const bf16x8*>(aBase + (2 * p + mm) * 1024 + sw1);
      }
      // ---- stage one half-tile (2 x global_load_lds), counted — never drained in loop
      if (p == 0) {
        load16_lds(aSt + ka, dstA);
        load16_lds(aSt + K64 + ka, dstA + 4096);
      } else if (p == 1) {
        load16_lds(aSt + 2 * K64 + ka, dstA + 8192);
        load16_lds(aSt + 3 * K64 + ka, dstA + 8192 + 4096);
      } else if (p == 2) {
        load16_lds(bSt + kb, dstB);
        load16_lds(bSt + K64 + kb, dstB + 4096);
      } else {
        load16_lds(bSt + 2 * K64 + kb, dstB + 8192);
        load16_lds(bSt + 3 * K64 + kb, dstB + 8192 + 4096);
      }

      __builtin_amdgcn_s_barrier();
      asm volatile("s_waitcnt lgkmcnt(0)" ::: "memory");
      __builtin_amdgcn_sched_barrier(0);

      __builtin_amdgcn_s_setprio(1);
#pragma unroll
      for (int mm = 0; mm < 2; ++mm) {
#pragma unroll
        for (int n = 0; n < 4; ++n) {
          acc[2 * p + mm][n] =
              __builtin_amdgcn_mfma_f32_16x16x32_bf16(af[mm][0], bfr[n][0], acc[2 * p + mm][n], 0, 0, 0);
          acc[2 * p + mm][n] =
              __builtin_amdgcn_mfma_f32_16x16x32_bf16(af[mm][1], bfr[n][1], acc[2 * p + mm][n], 0, 0, 0);
        }
      }
      __builtin_amdgcn_s_setprio(0);

      if (p == 3) {
        // retire A(t+1) (and older); keep B(t+2)'s 4 loads in flight
        asm volatile("s_waitcnt vmcnt(4)" ::: "memory");
      }
      __builtin_amdgcn_s_barrier();
    }
  }

  // ---- epilogue: D frag mapping col = lane&15, row = (lane>>4)*4 + j
  const int fr0 = q * 4;
#pragma unroll
  for (int m = 0; m < 8; ++m) {
#pragma unroll
    for (int n = 0; n < 4; ++n) {
      const int col = bn + wc * 64 + n * 16 + l15;
      const float bv = bias[col];
#pragma unroll
      for (int j = 0; j < 4; ++j) {
        const int row = bm + wr * 128 + m * 16 + fr0 + j;
        const float v = acc[m][n][j] + bv;
        if constexpr (MODE == 0) {
          outF[(size_t)row * N + col] = v;
        } else {
          const int t = col >> 10;          // 0:Q 1:K 2:V
          const int hh = (col >> 6) & 15;   // head
          const int d = col & 63;
          const int b = row >> 12;
          const int ss = row & 4095;
          unsigned short* dst = (t == 0) ? outQ : (t == 1) ? outK : outV;
          dst[((size_t)(b * NH + hh) * SEQ + ss) * HD_ + d] = f2bf(v);
        }
      }
    }
  }
}

// ---------------------------------------------------------------- grouping
// routes[s][0] == stable-argsort leader of the equal-Cantor-coord class.
// Verify exact row equality vs leader; mismatch -> singleton group.

__global__ void k_gid(const int* __restrict__ routes, int* __restrict__ gid, int* __restrict__ cnt) {
  const int s = blockIdx.x * 256 + threadIdx.x;
  const int lead = routes[s * 64];
  int g = s;
  if (lead >= 0 && lead < SEQ && lead != s) {
    bool eq = true;
    const int4* a = reinterpret_cast<const int4*>(routes + (size_t)s * 64);
    const int4* b = reinterpret_cast<const int4*>(routes + (size_t)lead * 64);
#pragma unroll
    for (int i = 0; i < 16; ++i) {
      int4 x = a[i], y = b[i];
      eq = eq && (x.x == y.x) && (x.y == y.y) && (x.z == y.z) && (x.w == y.w);
    }
    if (eq) g = lead;
  }
  gid[s] = g;
  atomicAdd(&cnt[g], 1);
}

__global__ void k_tilebase(const int* __restrict__ cnt, int* __restrict__ tileBase,
                           int* __restrict__ nTiles) {
  const int g = blockIdx.x * 256 + threadIdx.x;
  const int c = cnt[g];
  if (c > 0) {
    tileBase[g] = atomicAdd(nTiles, (c + 15) >> 4);
  }
}

__global__ void k_scatter(const int* __restrict__ gid, const int* __restrict__ tileBase,
                          int* __restrict__ pos, int* __restrict__ tileQ,
                          int* __restrict__ tileLead) {
  const int s = blockIdx.x * 256 + threadIdx.x;
  const int g = gid[s];
  const int p = atomicAdd(&pos[g], 1);
  const int tile = tileBase[g] + (p >> 4);
  tileQ[tile * 16 + (p & 15)] = s;
  if ((p & 15) == 0) tileLead[tile] = g;
}

// ---------------------------------------------------------------- grouped MFMA attention
// Block: 4 waves; wave w handles bh = blockIdx.y*8 + w*2 + {0,1} for tile blockIdx.x.
// Per wave: private 8KB KV LDS buffer (K for QK^T, then reused for V), P in stride-72 LDS.

__global__ __launch_bounds__(256)
void k_attn_grp(const unsigned short* __restrict__ Q,
                const unsigned short* __restrict__ Kb,
                const unsigned short* __restrict__ Vb,
                const int* __restrict__ routes,
                const int* __restrict__ tileQ,
                const int* __restrict__ tileLead,
                const int* __restrict__ nTilesPtr,
                unsigned short* __restrict__ att) {
  const int tile = blockIdx.x;
  if (tile >= *nTilesPtr) return;

  __shared__ int sMemRaw[16];
  __shared__ int sMemEff[16];
  __shared__ int sRoutes[64];
  __shared__ alignas(16) unsigned short sKV[4][4096];   // 32 KB
  __shared__ alignas(16) unsigned short sP[4][16 * 72]; // 9216 B

  const int tid = threadIdx.x;
  if (tid < 16) {
    const int v = tileQ[tile * 16 + tid];
    const int v0 = tileQ[tile * 16];
    sMemRaw[tid] = v;
    sMemEff[tid] = (v < 0) ? v0 : v;
  } else if (tid >= 64 && tid < 128) {
    const int lead = tileLead[tile];
    sRoutes[tid - 64] = routes[(size_t)lead * 64 + (tid - 64)];
  }
  __syncthreads();

  const int wave = tid >> 6, lane = tid & 63;
  unsigned short* KV = sKV[wave];
  unsigned short* P = sP[wave];
  const int hi = lane >> 4;    // 0..3
  const int l15 = lane & 15;
  const int l7 = lane & 7;
  const int rr = lane >> 3;    // 0..7 (staging row-in-iter)

#pragma unroll 1
  for (int ih = 0; ih < 2; ++ih) {
    const int bh = blockIdx.y * 8 + wave * 2 + ih;
    const size_t base = (size_t)bh * (SEQ * HD_);

    __builtin_amdgcn_s_waitcnt(0);
    __builtin_amdgcn_sched_barrier(0);

    // ---- stage K (rot8). src chunk = (c' - (k&7)) & 7, k&7 == rr
    {
      const int sc = ((l7 - rr) & 7) * 8;
#pragma unroll
      for (int t = 0; t < 8; ++t) {
        const int rk = sRoutes[t * 8 + rr];
        load16_lds(Kb + base + (size_t)rk * HD_ + sc, &KV[t * 512]);
      }
    }

    // ---- Q fragments direct from global
    bf16x8 qa0, qa1;
    {
      const unsigned short* qrow = Q + base + (size_t)sMemEff[l15] * HD_ + hi * 8;
      qa0 = *reinterpret_cast<const bf16x8*>(qrow);
      qa1 = *reinterpret_cast<const bf16x8*>(qrow + 32);
    }
    __builtin_amdgcn_s_waitcnt(0);
    __builtin_amdgcn_sched_barrier(0);

    // ---- QK^T
    f32x4 accS[4] = {};
#pragma unroll
    for (int nb = 0; nb < 4; ++nb) {
      const int key = nb * 16 + l15;
      const int rot = 8 * (key & 7);
      const int ae0 = key * 64 + (((hi * 8) + rot) & 63);
      const int ae1 = key * 64 + (((32 + hi * 8) + rot) & 63);
      bf16x8 kf0 = *reinterpret_cast<const bf16x8*>(&KV[ae0]);
      bf16x8 kf1 = *reinterpret_cast<const bf16x8*>(&KV[ae1]);
      accS[nb] = __builtin_amdgcn_mfma_f32_16x16x32_bf16(qa0, kf0, accS[nb], 0, 0, 0);
      accS[nb] = __builtin_amdgcn_mfma_f32_16x16x32_bf16(qa1, kf1, accS[nb], 0, 0, 0);
    }

    // ---- softmax per row
#pragma unroll
    for (int jj = 0; jj < 4; ++jj) {
      float m = fmaxf(fmaxf(accS[0][jj], accS[1][jj]), fmaxf(accS[2][jj], accS[3][jj]));
#pragma unroll
      for (int o = 1; o < 16; o <<= 1) m = fmaxf(m, __shfl_xor(m, o));
      const float e0 = __expf((accS[0][jj] - m) * SCALE_);
      const float e1 = __expf((accS[1][jj] - m) * SCALE_);
      const float e2 = __expf((accS[2][jj] - m) * SCALE_);
      const float e3 = __expf((accS[3][jj] - m) * SCALE_);
      float sum = (e0 + e1) + (e2 + e3);
#pragma unroll
      for (int o = 1; o < 16; o <<= 1) sum += __shfl_xor(sum, o);
      const float rs = __builtin_amdgcn_rcpf(sum);
      const int row = hi * 4 + jj;
      P[row * 72 + 0 + l15] = f2bf(e0 * rs);
      P[row * 72 + 16 + l15] = f2bf(e1 * rs);
      P[row * 72 + 32 + l15] = f2bf(e2 * rs);
      P[row * 72 + 48 + l15] = f2bf(e3 * rs);
    }

    // ---- stage V (rot16) into same KV buffer
    asm volatile("s_waitcnt lgkmcnt(0)" ::: "memory");
    __builtin_amdgcn_sched_barrier(0);
    {
#pragma unroll
      for (int t = 0; t < 8; ++t) {
        const int rk = sRoutes[t * 8 + rr];
        const int sc = ((l7 - 2 * (t & 3)) & 7) * 8;
        load16_lds(Vb + base + (size_t)rk * HD_ + sc, &KV[t * 512]);
      }
    }
    __builtin_amdgcn_s_waitcnt(0);
    __builtin_amdgcn_sched_barrier(0);

    // ---- PV
    f32x4 accO[4] = {};
#pragma unroll
    for (int ks = 0; ks < 2; ++ks) {
      bf16x8 pf = *reinterpret_cast<const bf16x8*>(&P[l15 * 72 + ks * 32 + hi * 8]);
#pragma unroll
      for (int nb = 0; nb < 4; ++nb) {
        const int d = nb * 16 + l15;
        const int rot = (d + 16 * hi) & 63;
        bf16x8 vf;
#pragma unroll
        for (int j = 0; j < 8; ++j) {
          const int k = ks * 32 + hi * 8 + j;
          vf[j] = *reinterpret_cast<const __bf16*>(&KV[k * 64 + rot]);
        }
        accO[nb] = __builtin_amdgcn_mfma_f32_16x16x32_bf16(pf, vf, accO[nb], 0, 0, 0);
      }
    }

    // ---- epilogue: att[b][s][h*64 + d]
    const int b = bh >> 4, h = bh & 15;
#pragma unroll
    for (int jj = 0; jj < 4; ++jj) {
      const int sQ = sMemRaw[hi * 4 + jj];
      if (sQ >= 0) {
#pragma unroll
        for (int nb = 0; nb < 4; ++nb) {
          att[((size_t)(b * SEQ + sQ)) * DIM_ + h * HD_ + nb * 16 + l15] = f2bf(accO[nb][jj]);
        }
      }
    }
  }
}

// ---------------------------------------------------------------- launch

extern "C" void kernel_launch(void* const* d_in, const int* in_sizes, int n_in,
                              void* d_out, int out_size, void* d_ws, size_t ws_size,
                              hipStream_t stream) {
  (void)in_sizes; (void)n_in; (void)out_size; (void)ws_size;
  const float* x      = (const float*)d_in[0];
  const float* Wqkv   = (const float*)d_in[1];
  const float* bqkv   = (const float*)d_in[2];
  const float* Wout   = (const float*)d_in[3];
  const float* bout   = (const float*)d_in[4];
  const int*   routes = (const int*)d_in[5];
  float* out = (float*)d_out;

  uint8_t* ws = (uint8_t*)d_ws;
  unsigned short* wqkvT = (unsigned short*)(ws);              //  6,291,456 B (3072x1024 bf16)
  unsigned short* woutT = (unsigned short*)(ws + 6291456);    //  2,097,152 B (1024x1024 bf16)
  unsigned short* Qb    = (unsigned short*)(ws + 8388608);    // 16 MiB
  unsigned short* Kb    = (unsigned short*)(ws + 25165824);   // 16 MiB
  unsigned short* Vb    = (unsigned short*)(ws + 41943040);   // 16 MiB
  unsigned short* att   = (unsigned short*)(ws + 58720256);   // 16 MiB (end 75,497,472)

  // d_out (32 MiB f32): first 16 MiB = xb (dead after GEMM1); second half holds group
  // metadata (dead before GEMM2's output store touches it).
  unsigned short* xb = (unsigned short*)d_out;
  uint8_t* g0 = (uint8_t*)d_out + (16u << 20);
  int* gidArr   = (int*)(g0);                 // 16 KB
  int* cnt      = (int*)(g0 + 16384);         // 16 KB
  int* pos      = (int*)(g0 + 32768);         // 16 KB
  int* tileBase = (int*)(g0 + 49152);         // 16 KB
  int* nTiles   = (int*)(g0 + 65536);         // 4 B
  int* tileLead = (int*)(g0 + 81920);         // 16 KB
  int* tileQ    = (int*)(g0 + 98304);         // 256 KB

  hipMemsetAsync(cnt, 0, 16384, stream);
  hipMemsetAsync(pos, 0, 16384, stream);
  hipMemsetAsync(nTiles, 0, 4, stream);
  hipMemsetAsync(tileQ, 0xFF, 4096 * 16 * 4, stream);

  k_gid<<<16, 256, 0, stream>>>(routes, gidArr, cnt);
  k_tilebase<<<16, 256, 0, stream>>>(cnt, tileBase, nTiles);
  k_scatter<<<16, 256, 0, stream>>>(gidArr, tileBase, pos, tileQ, tileLead);

  k_cvt_bf16<<<8192, 256, 0, stream>>>(x, xb);
  k_transpose_cvt<<<dim3(48, 16), 256, 0, stream>>>(Wqkv, wqkvT, 1024, 3072);
  k_transpose_cvt<<<dim3(16, 16), 256, 0, stream>>>(Wout, woutT, 1024, 1024);

  k_gemm8p<1><<<dim3(32, 12), 512, 0, stream>>>(xb, wqkvT, bqkv, nullptr, Qb, Kb, Vb,
                                                8192, 3072, 1024);
  k_attn_grp<<<dim3(4096, 4), 256, 0, stream>>>(Qb, Kb, Vb, routes, tileQ, tileLead,
                                                nTiles, att);
  k_gemm8p<0><<<dim3(32, 4), 512, 0, stream>>>(att, woutT, bout, out,
                                               nullptr, nullptr, nullptr, 8192, 1024, 1024);
}